// Round 1
// baseline (1031.009 us; speedup 1.0000x reference)
//
#include <hip/hip_runtime.h>
#include <hip/hip_bf16.h>

// GCN: 3 layers of  h = relu(in_norm * A_pull( (out_norm*x) @ W ) + b)
// then seg_output = (mean_n h3) @ Wp^T + bp  and  CAM = Wp @ h3^T.
// Strategy: build CSR (by dst) once per call, pull-aggregate (no float atomics).

#define HDIM 128
#define NCLS 40

// ---------------- graph preprocessing ----------------

__global__ void zero_kernel(int* __restrict__ p, int n) {
    int i = blockIdx.x * blockDim.x + threadIdx.x;
    if (i < n) p[i] = 0;
}

__global__ void deg_kernel(const int* __restrict__ src, const int* __restrict__ dst,
                           int* __restrict__ out_deg, int* __restrict__ in_deg, int E) {
    int i = blockIdx.x * blockDim.x + threadIdx.x;
    if (i < E) {
        atomicAdd(&out_deg[src[i]], 1);
        atomicAdd(&in_deg[dst[i]], 1);
    }
}

__global__ void norm_kernel(const int* __restrict__ out_deg, const int* __restrict__ in_deg,
                            float* __restrict__ out_norm, float* __restrict__ in_norm, int n) {
    int i = blockIdx.x * blockDim.x + threadIdx.x;
    if (i < n) {
        out_norm[i] = 1.0f / sqrtf((float)max(out_deg[i], 1));
        in_norm[i]  = 1.0f / sqrtf((float)max(in_deg[i], 1));
    }
}

// exclusive scan of in_deg -> row_ptr, single block of 1024 threads, 4 elems/thread/chunk
__global__ void scan_kernel(const int* __restrict__ cnt, int* __restrict__ row_ptr, int n) {
    __shared__ int wsum[16];
    __shared__ int chunk_total;
    const int tid = threadIdx.x;           // 0..1023
    const int lane = tid & 63, wid = tid >> 6;
    int carry = 0;
    for (int base = 0; base < n; base += 4096) {
        int idx = base + tid * 4;
        int v0 = (idx     < n) ? cnt[idx]     : 0;
        int v1 = (idx + 1 < n) ? cnt[idx + 1] : 0;
        int v2 = (idx + 2 < n) ? cnt[idx + 2] : 0;
        int v3 = (idx + 3 < n) ? cnt[idx + 3] : 0;
        int s = v0 + v1 + v2 + v3;
        int incl = s;
        #pragma unroll
        for (int d = 1; d < 64; d <<= 1) {
            int o = __shfl_up(incl, d, 64);
            if (lane >= d) incl += o;
        }
        if (lane == 63) wsum[wid] = incl;
        __syncthreads();
        if (wid == 0 && lane < 16) {
            int ws = wsum[lane];
            int wi = ws;
            #pragma unroll
            for (int d = 1; d < 16; d <<= 1) {
                int o = __shfl_up(wi, d, 64);
                if (lane >= d) wi += o;
            }
            wsum[lane] = wi - ws;          // exclusive wave offset
            if (lane == 15) chunk_total = wi;
        }
        __syncthreads();
        int excl = carry + wsum[wid] + incl - s;
        if (idx     < n) row_ptr[idx]     = excl;
        if (idx + 1 < n) row_ptr[idx + 1] = excl + v0;
        if (idx + 2 < n) row_ptr[idx + 2] = excl + v0 + v1;
        if (idx + 3 < n) row_ptr[idx + 3] = excl + v0 + v1 + v2;
        carry += chunk_total;
        __syncthreads();                   // protect wsum/chunk_total reuse
    }
    if (tid == 0) row_ptr[n] = carry;
}

__global__ void fill_kernel(const int* __restrict__ src, const int* __restrict__ dst,
                            const int* __restrict__ row_ptr, int* __restrict__ fill_cnt,
                            int* __restrict__ col, int E) {
    int i = blockIdx.x * blockDim.x + threadIdx.x;
    if (i < E) {
        int d = dst[i];
        int p = atomicAdd(&fill_cnt[d], 1);
        col[row_ptr[d] + p] = src[i];
    }
}

// ---------------- dense compute ----------------

// out[n,:] = (out_norm[n] * x[n,:]) @ W   — 64 rows/block, W staged in 2 K-halves.
// LDS = 64 KB exactly -> 2 blocks/CU.
__global__ __launch_bounds__(256, 2) void gemm_kernel(
        const float* __restrict__ x, const float* __restrict__ W,
        const float* __restrict__ out_norm, float* __restrict__ out, int n) {
    __shared__ float xs[64 * 128];    // 32 KB: full K for 64 rows
    __shared__ float wsm[64 * 128];   // 32 KB: half-K of W
    const int tid = threadIdx.x;
    const int row0 = blockIdx.x * 64;

    for (int t = tid; t < 64 * 32; t += 256) {
        int r = t >> 5, c4 = t & 31;
        int gr = row0 + r;
        float4 v = {0.f, 0.f, 0.f, 0.f};
        if (gr < n) {
            v = ((const float4*)(x + (size_t)gr * HDIM))[c4];
            float s = out_norm[gr];
            v.x *= s; v.y *= s; v.z *= s; v.w *= s;
        }
        *(float4*)&xs[r * 128 + c4 * 4] = v;
    }

    const int cg = tid & 15, rg = tid >> 4;
    const int c0 = cg * 8, r0 = rg * 4;
    float acc[4][8] = {};

    for (int kh = 0; kh < 2; ++kh) {
        __syncthreads();   // xs ready (kh=0) / previous compute done before wsm overwrite
        for (int t = tid; t < 64 * 32; t += 256)
            ((float4*)wsm)[t] = ((const float4*)(W + kh * 64 * HDIM))[t];
        __syncthreads();
        #pragma unroll 4
        for (int kk = 0; kk < 64; ++kk) {
            int k = kh * 64 + kk;
            float xv[4];
            #pragma unroll
            for (int i = 0; i < 4; ++i) xv[i] = xs[(r0 + i) * 128 + k];
            float wv[8];
            *(float4*)&wv[0] = *(const float4*)&wsm[kk * 128 + c0];
            *(float4*)&wv[4] = *(const float4*)&wsm[kk * 128 + c0 + 4];
            #pragma unroll
            for (int i = 0; i < 4; ++i)
                #pragma unroll
                for (int j = 0; j < 8; ++j)
                    acc[i][j] = fmaf(xv[i], wv[j], acc[i][j]);
        }
    }

    #pragma unroll
    for (int i = 0; i < 4; ++i) {
        int gr = row0 + r0 + i;
        if (gr < n) {
            float4 v0 = {acc[i][0], acc[i][1], acc[i][2], acc[i][3]};
            float4 v1 = {acc[i][4], acc[i][5], acc[i][6], acc[i][7]};
            float4* op = (float4*)(out + (size_t)gr * HDIM + c0);
            op[0] = v0; op[1] = v1;
        }
    }
}

// h[n,:] = relu(in_norm[n] * sum_{e in CSR[n]} t[col[e],:] + b)  — one wave per node.
__global__ __launch_bounds__(256) void agg_kernel(
        const float* __restrict__ t, const int* __restrict__ row_ptr,
        const int* __restrict__ col, const float* __restrict__ in_norm,
        const float* __restrict__ bias, float* __restrict__ h, int n) {
    int node = blockIdx.x * 4 + (threadIdx.x >> 6);
    if (node >= n) return;
    const int lane = threadIdx.x & 63;
    const int beg = row_ptr[node], end = row_ptr[node + 1];
    float2 acc0 = {0.f, 0.f}, acc1 = {0.f, 0.f};
    for (int e = beg; e < end; e += 64) {
        int cnt = min(64, end - e);
        int ci = 0;
        if (lane < cnt) ci = col[e + lane];
        int j = 0;
        for (; j + 1 < cnt; j += 2) {
            int s0 = __shfl(ci, j, 64);
            int s1 = __shfl(ci, j + 1, 64);
            float2 v0 = ((const float2*)(t + (size_t)s0 * HDIM))[lane];
            float2 v1 = ((const float2*)(t + (size_t)s1 * HDIM))[lane];
            acc0.x += v0.x; acc0.y += v0.y;
            acc1.x += v1.x; acc1.y += v1.y;
        }
        if (j < cnt) {
            int s0 = __shfl(ci, j, 64);
            float2 v0 = ((const float2*)(t + (size_t)s0 * HDIM))[lane];
            acc0.x += v0.x; acc0.y += v0.y;
        }
    }
    float inn = in_norm[node];
    float2 bb = ((const float2*)bias)[lane];
    float2 res;
    res.x = fmaxf((acc0.x + acc1.x) * inn + bb.x, 0.f);
    res.y = fmaxf((acc0.y + acc1.y) * inn + bb.y, 0.f);
    ((float2*)(h + (size_t)node * HDIM))[lane] = res;
}

// column sums of h (for mean over nodes)
__global__ void colsum_kernel(const float* __restrict__ h, float* __restrict__ colsum, int n) {
    int c = threadIdx.x & 127;
    int rstart = blockIdx.x * 2 + (threadIdx.x >> 7);
    float s = 0.f;
    for (int r = rstart; r < n; r += gridDim.x * 2)
        s += h[(size_t)r * HDIM + c];
    atomicAdd(&colsum[c], s);
}

__global__ void seg_kernel(const float* __restrict__ colsum, const float* __restrict__ Wp,
                           const float* __restrict__ bp, float* __restrict__ segout, float inv_n) {
    int c = threadIdx.x;
    if (c < NCLS) {
        float s = 0.f;
        #pragma unroll 4
        for (int k = 0; k < HDIM; ++k) s = fmaf(colsum[k], Wp[c * HDIM + k], s);
        segout[c] = s * inv_n + bp[c];
    }
}

// CAM[c, n] = dot(Wp[c,:], h[n,:]) — 64 nodes/block, Wp + h-tile in LDS.
__global__ __launch_bounds__(256) void cam_kernel(
        const float* __restrict__ h, const float* __restrict__ Wp,
        float* __restrict__ out, int n) {
    __shared__ float hs[64][132];          // +4 pad
    __shared__ float wp[NCLS * HDIM];      // 20.5 KB
    const int tid = threadIdx.x;
    const int n0 = blockIdx.x * 64;
    for (int t = tid; t < NCLS * 32; t += 256)
        ((float4*)wp)[t] = ((const float4*)Wp)[t];
    for (int t = tid; t < 64 * 32; t += 256) {
        int r = t >> 5, c4 = t & 31;
        float4 v = {0.f, 0.f, 0.f, 0.f};
        if (n0 + r < n) v = ((const float4*)(h + (size_t)(n0 + r) * HDIM))[c4];
        *(float4*)&hs[r][c4 * 4] = v;
    }
    __syncthreads();
    const int nl = tid & 63;               // node in tile
    const int cb = (tid >> 6) * 10;        // 10 classes per wave
    float acc[10] = {};
    for (int k = 0; k < HDIM; k += 4) {
        float4 hv = *(const float4*)&hs[nl][k];
        #pragma unroll
        for (int c = 0; c < 10; ++c) {
            float4 wv = *(const float4*)&wp[(cb + c) * HDIM + k];
            acc[c] = fmaf(hv.x, wv.x, acc[c]);
            acc[c] = fmaf(hv.y, wv.y, acc[c]);
            acc[c] = fmaf(hv.z, wv.z, acc[c]);
            acc[c] = fmaf(hv.w, wv.w, acc[c]);
        }
    }
    int gn = n0 + nl;
    if (gn < n) {
        #pragma unroll
        for (int c = 0; c < 10; ++c)
            out[(size_t)(cb + c) * n + gn] = acc[c];
    }
}

// ---------------- launch ----------------

extern "C" void kernel_launch(void* const* d_in, const int* in_sizes, int n_in,
                              void* d_out, int out_size, void* d_ws, size_t ws_size,
                              hipStream_t stream) {
    const float* features = (const float*)d_in[0];
    const float* W1 = (const float*)d_in[1];
    const float* b1 = (const float*)d_in[2];
    const float* W2 = (const float*)d_in[3];
    const float* b2 = (const float*)d_in[4];
    const float* W3 = (const float*)d_in[5];
    const float* b3 = (const float*)d_in[6];
    const float* Wp = (const float*)d_in[7];
    const float* bp = (const float*)d_in[8];
    const int*   src = (const int*)d_in[9];
    const int*   dst = (const int*)d_in[10];

    const int N = in_sizes[0] / HDIM;
    const int E = in_sizes[9];
    float* out = (float*)d_out;

    // workspace carve-up
    char* ws = (char*)d_ws;
    size_t off = 0;
    int* out_deg  = (int*)(ws + off); off += (size_t)N * 4;
    int* in_deg   = (int*)(ws + off); off += (size_t)N * 4;
    int* fill_cnt = (int*)(ws + off); off += (size_t)N * 4;
    float* colsum = (float*)(ws + off); off += 128 * 4;
    int* row_ptr  = (int*)(ws + off); off += ((size_t)N + 1) * 4; off = (off + 15) & ~(size_t)15;
    int* col_idx  = (int*)(ws + off); off += (size_t)E * 4; off = (off + 15) & ~(size_t)15;
    float* out_norm = (float*)(ws + off); off += (size_t)N * 4;
    float* in_norm  = (float*)(ws + off); off += (size_t)N * 4; off = (off + 255) & ~(size_t)255;
    float* B1 = (float*)(ws + off); off += (size_t)N * HDIM * 4;
    float* B0 = (float*)(ws + off); off += (size_t)N * HDIM * 4;
    (void)ws_size; (void)n_in; (void)out_size;

    const int nzero = 3 * N + 128;
    zero_kernel<<<(nzero + 255) / 256, 256, 0, stream>>>((int*)ws, nzero);
    deg_kernel<<<(E + 255) / 256, 256, 0, stream>>>(src, dst, out_deg, in_deg, E);
    norm_kernel<<<(N + 255) / 256, 256, 0, stream>>>(out_deg, in_deg, out_norm, in_norm, N);
    scan_kernel<<<1, 1024, 0, stream>>>(in_deg, row_ptr, N);
    fill_kernel<<<(E + 255) / 256, 256, 0, stream>>>(src, dst, row_ptr, fill_cnt, col_idx, E);

    const int gemm_blocks = (N + 63) / 64;
    const int agg_blocks  = (N + 3) / 4;

    // layer 1
    gemm_kernel<<<gemm_blocks, 256, 0, stream>>>(features, W1, out_norm, B1, N);
    agg_kernel<<<agg_blocks, 256, 0, stream>>>(B1, row_ptr, col_idx, in_norm, b1, B0, N);
    // layer 2
    gemm_kernel<<<gemm_blocks, 256, 0, stream>>>(B0, W2, out_norm, B1, N);
    agg_kernel<<<agg_blocks, 256, 0, stream>>>(B1, row_ptr, col_idx, in_norm, b2, B0, N);
    // layer 3
    gemm_kernel<<<gemm_blocks, 256, 0, stream>>>(B0, W3, out_norm, B1, N);
    agg_kernel<<<agg_blocks, 256, 0, stream>>>(B1, row_ptr, col_idx, in_norm, b3, B0, N);

    // head
    colsum_kernel<<<512, 256, 0, stream>>>(B0, colsum, N);
    seg_kernel<<<1, 64, 0, stream>>>(colsum, Wp, bp, out, 1.0f / (float)N);
    cam_kernel<<<(N + 63) / 64, 256, 0, stream>>>(B0, Wp, out + NCLS, N);
}

// Round 2
// 922.889 us; speedup vs baseline: 1.1172x; 1.1172x over previous
//
#include <hip/hip_runtime.h>
#include <hip/hip_bf16.h>

// GCN: 3 layers of  h = relu(in_norm * A_pull( (out_norm*x) @ W ) + b)
// then seg_output = (mean_n h3) @ Wp^T + bp  and  CAM = Wp @ h3^T.
// CSR built per call: deg atomics also yield per-edge slot (pos) -> fill is atomic-free.

#define HDIM 128
#define NCLS 40

// ---------------- graph preprocessing ----------------

__global__ void zero_kernel(int* __restrict__ p, int n) {
    int i = blockIdx.x * blockDim.x + threadIdx.x;
    if (i < n) p[i] = 0;
}

// degrees + per-edge slot within dst row (pos). 4 edges/thread.
__global__ void deg_kernel(const int* __restrict__ src, const int* __restrict__ dst,
                           int* __restrict__ out_deg, int* __restrict__ in_deg,
                           int* __restrict__ pos, int E) {
    int i4 = (blockIdx.x * blockDim.x + threadIdx.x) * 4;
    if (i4 + 3 < E) {
        int4 s = *(const int4*)(src + i4);
        int4 d = *(const int4*)(dst + i4);
        atomicAdd(&out_deg[s.x], 1);
        atomicAdd(&out_deg[s.y], 1);
        atomicAdd(&out_deg[s.z], 1);
        atomicAdd(&out_deg[s.w], 1);
        int4 p;
        p.x = atomicAdd(&in_deg[d.x], 1);
        p.y = atomicAdd(&in_deg[d.y], 1);
        p.z = atomicAdd(&in_deg[d.z], 1);
        p.w = atomicAdd(&in_deg[d.w], 1);
        *(int4*)(pos + i4) = p;
    } else {
        for (int i = i4; i < E; ++i) {
            atomicAdd(&out_deg[src[i]], 1);
            pos[i] = atomicAdd(&in_deg[dst[i]], 1);
        }
    }
}

__global__ void norm_kernel(const int* __restrict__ out_deg, const int* __restrict__ in_deg,
                            float* __restrict__ out_norm, float* __restrict__ in_norm, int n) {
    int i = blockIdx.x * blockDim.x + threadIdx.x;
    if (i < n) {
        out_norm[i] = 1.0f / sqrtf((float)max(out_deg[i], 1));
        in_norm[i]  = 1.0f / sqrtf((float)max(in_deg[i], 1));
    }
}

// ---- 3-pass exclusive scan over in_deg -> row_ptr ----

// block b sums elements [b*1024, b*1024+1024)
__global__ void scan_part_kernel(const int* __restrict__ cnt, int* __restrict__ bsum, int n) {
    const int tid = threadIdx.x;
    int base = blockIdx.x * 1024 + tid * 4;
    int s = 0;
    #pragma unroll
    for (int j = 0; j < 4; ++j) if (base + j < n) s += cnt[base + j];
    #pragma unroll
    for (int d = 1; d < 64; d <<= 1) s += __shfl_down(s, d, 64);
    __shared__ int ws[4];
    if ((tid & 63) == 0) ws[tid >> 6] = s;
    __syncthreads();
    if (tid == 0) bsum[blockIdx.x] = ws[0] + ws[1] + ws[2] + ws[3];
}

// single block of 128 threads: exclusive scan of bsum[0..P), total -> row_ptr[n]
__global__ void scan_mid_kernel(const int* __restrict__ bsum, int* __restrict__ psum,
                                int* __restrict__ row_ptr, int P, int n) {
    const int tid = threadIdx.x;            // 0..127
    const int lane = tid & 63, w = tid >> 6;
    int v = (tid < P) ? bsum[tid] : 0;
    int incl = v;
    #pragma unroll
    for (int d = 1; d < 64; d <<= 1) {
        int o = __shfl_up(incl, d, 64);
        if (lane >= d) incl += o;
    }
    __shared__ int wtot[2];
    if (lane == 63) wtot[w] = incl;
    __syncthreads();
    int off = (w == 1) ? wtot[0] : 0;
    if (tid < P) psum[tid] = off + incl - v;
    if (tid == 0) row_ptr[n] = wtot[0] + wtot[1];
}

// block b: exclusive scan of its 1024 elements, offset by psum[b]
__global__ void scan_local_kernel(const int* __restrict__ cnt, const int* __restrict__ psum,
                                  int* __restrict__ row_ptr, int n) {
    const int tid = threadIdx.x;
    const int lane = tid & 63, w = tid >> 6;
    int base = blockIdx.x * 1024 + tid * 4;
    int v0 = (base     < n) ? cnt[base]     : 0;
    int v1 = (base + 1 < n) ? cnt[base + 1] : 0;
    int v2 = (base + 2 < n) ? cnt[base + 2] : 0;
    int v3 = (base + 3 < n) ? cnt[base + 3] : 0;
    int s = v0 + v1 + v2 + v3;
    int incl = s;
    #pragma unroll
    for (int d = 1; d < 64; d <<= 1) {
        int o = __shfl_up(incl, d, 64);
        if (lane >= d) incl += o;
    }
    __shared__ int ws[4];
    if (lane == 63) ws[w] = incl;
    __syncthreads();
    int off = psum[blockIdx.x];
    for (int j = 0; j < w; ++j) off += ws[j];
    int excl = off + incl - s;
    if (base     < n) row_ptr[base]     = excl;
    if (base + 1 < n) row_ptr[base + 1] = excl + v0;
    if (base + 2 < n) row_ptr[base + 2] = excl + v0 + v1;
    if (base + 3 < n) row_ptr[base + 3] = excl + v0 + v1 + v2;
}

// atomic-free CSR fill using precomputed pos
__global__ void fill_kernel(const int* __restrict__ src, const int* __restrict__ dst,
                            const int* __restrict__ row_ptr, const int* __restrict__ pos,
                            int* __restrict__ col, int E) {
    int i4 = (blockIdx.x * blockDim.x + threadIdx.x) * 4;
    if (i4 + 3 < E) {
        int4 s = *(const int4*)(src + i4);
        int4 d = *(const int4*)(dst + i4);
        int4 p = *(const int4*)(pos + i4);
        col[row_ptr[d.x] + p.x] = s.x;
        col[row_ptr[d.y] + p.y] = s.y;
        col[row_ptr[d.z] + p.z] = s.z;
        col[row_ptr[d.w] + p.w] = s.w;
    } else {
        for (int i = i4; i < E; ++i)
            col[row_ptr[dst[i]] + pos[i]] = src[i];
    }
}

// ---------------- dense compute ----------------

// out[n,:] = (out_norm[n] * x[n,:]) @ W   — 64 rows/block, W staged in 2 K-halves.
// xs stride 132 breaks bank aliasing; x-fragments read as b128 per 4 k-steps.
__global__ __launch_bounds__(256, 2) void gemm_kernel(
        const float* __restrict__ x, const float* __restrict__ W,
        const float* __restrict__ out_norm, float* __restrict__ out, int n) {
    __shared__ float xs[64 * 132];    // ~33 KB
    __shared__ float wsm[64 * 128];   // 32 KB
    const int tid = threadIdx.x;
    const int row0 = blockIdx.x * 64;

    for (int t = tid; t < 64 * 32; t += 256) {
        int r = t >> 5, c4 = t & 31;
        int gr = row0 + r;
        float4 v = {0.f, 0.f, 0.f, 0.f};
        if (gr < n) {
            v = ((const float4*)(x + (size_t)gr * HDIM))[c4];
            float s = out_norm[gr];
            v.x *= s; v.y *= s; v.z *= s; v.w *= s;
        }
        *(float4*)&xs[r * 132 + c4 * 4] = v;
    }

    const int cg = tid & 15, rg = tid >> 4;
    const int c0 = cg * 8, r0 = rg * 4;
    float acc[4][8] = {};

    for (int kh = 0; kh < 2; ++kh) {
        __syncthreads();   // xs ready (kh=0) / previous compute done before wsm overwrite
        for (int t = tid; t < 64 * 32; t += 256)
            ((float4*)wsm)[t] = ((const float4*)(W + kh * 64 * HDIM))[t];
        __syncthreads();
        #pragma unroll 2
        for (int kk4 = 0; kk4 < 16; ++kk4) {
            float xr[4][4];
            #pragma unroll
            for (int i = 0; i < 4; ++i)
                *(float4*)&xr[i][0] = *(const float4*)&xs[(r0 + i) * 132 + kh * 64 + kk4 * 4];
            #pragma unroll
            for (int q = 0; q < 4; ++q) {
                float wv[8];
                *(float4*)&wv[0] = *(const float4*)&wsm[(kk4 * 4 + q) * 128 + c0];
                *(float4*)&wv[4] = *(const float4*)&wsm[(kk4 * 4 + q) * 128 + c0 + 4];
                #pragma unroll
                for (int i = 0; i < 4; ++i)
                    #pragma unroll
                    for (int j = 0; j < 8; ++j)
                        acc[i][j] = fmaf(xr[i][q], wv[j], acc[i][j]);
            }
        }
    }

    #pragma unroll
    for (int i = 0; i < 4; ++i) {
        int gr = row0 + r0 + i;
        if (gr < n) {
            float4 v0 = {acc[i][0], acc[i][1], acc[i][2], acc[i][3]};
            float4 v1 = {acc[i][4], acc[i][5], acc[i][6], acc[i][7]};
            float4* op = (float4*)(out + (size_t)gr * HDIM + c0);
            op[0] = v0; op[1] = v1;
        }
    }
}

// h[n,:] = relu(in_norm[n]*sum t[col[e],:] + b) — one wave/node, half-wave per edge, float4 lanes.
__global__ __launch_bounds__(256) void agg_kernel(
        const float* __restrict__ t, const int* __restrict__ row_ptr,
        const int* __restrict__ col, const float* __restrict__ in_norm,
        const float* __restrict__ bias, float* __restrict__ h, int n) {
    int node = blockIdx.x * 4 + (threadIdx.x >> 6);
    if (node >= n) return;
    const int lane = threadIdx.x & 63;
    const int half = lane >> 5;     // which edge of the pair
    const int fl = lane & 31;       // float4 index within the 128-feature row
    const int beg = row_ptr[node], end = row_ptr[node + 1];
    float4 acc0 = {0.f, 0.f, 0.f, 0.f}, acc1 = {0.f, 0.f, 0.f, 0.f};
    for (int e = beg; e < end; e += 64) {
        int cnt = min(64, end - e);
        int ci = (lane < cnt) ? col[e + lane] : 0;
        int j = 0;
        for (; j + 3 < cnt; j += 4) {
            int s0 = __shfl(ci, j + half, 64);
            int s1 = __shfl(ci, j + 2 + half, 64);
            float4 v0 = ((const float4*)(t + (size_t)s0 * HDIM))[fl];
            float4 v1 = ((const float4*)(t + (size_t)s1 * HDIM))[fl];
            acc0.x += v0.x; acc0.y += v0.y; acc0.z += v0.z; acc0.w += v0.w;
            acc1.x += v1.x; acc1.y += v1.y; acc1.z += v1.z; acc1.w += v1.w;
        }
        for (; j + 1 < cnt; j += 2) {
            int s0 = __shfl(ci, j + half, 64);
            float4 v0 = ((const float4*)(t + (size_t)s0 * HDIM))[fl];
            acc0.x += v0.x; acc0.y += v0.y; acc0.z += v0.z; acc0.w += v0.w;
        }
        if (j < cnt) {
            int s0 = __shfl(ci, j, 64);
            if (half == 0) {
                float4 v0 = ((const float4*)(t + (size_t)s0 * HDIM))[fl];
                acc0.x += v0.x; acc0.y += v0.y; acc0.z += v0.z; acc0.w += v0.w;
            }
        }
    }
    acc0.x += acc1.x; acc0.y += acc1.y; acc0.z += acc1.z; acc0.w += acc1.w;
    // fold upper half into lower half (4 shuffles)
    float ox = __shfl(acc0.x, fl + 32, 64);
    float oy = __shfl(acc0.y, fl + 32, 64);
    float oz = __shfl(acc0.z, fl + 32, 64);
    float ow = __shfl(acc0.w, fl + 32, 64);
    if (half == 0) {
        float inn = in_norm[node];
        float4 bb = ((const float4*)bias)[fl];
        float4 res;
        res.x = fmaxf((acc0.x + ox) * inn + bb.x, 0.f);
        res.y = fmaxf((acc0.y + oy) * inn + bb.y, 0.f);
        res.z = fmaxf((acc0.z + oz) * inn + bb.z, 0.f);
        res.w = fmaxf((acc0.w + ow) * inn + bb.w, 0.f);
        ((float4*)(h + (size_t)node * HDIM))[fl] = res;
    }
}

// column sums of h (for mean over nodes)
__global__ void colsum_kernel(const float* __restrict__ h, float* __restrict__ colsum, int n) {
    int c = threadIdx.x & 127;
    int rstart = blockIdx.x * 2 + (threadIdx.x >> 7);
    float s = 0.f;
    for (int r = rstart; r < n; r += gridDim.x * 2)
        s += h[(size_t)r * HDIM + c];
    atomicAdd(&colsum[c], s);
}

__global__ void seg_kernel(const float* __restrict__ colsum, const float* __restrict__ Wp,
                           const float* __restrict__ bp, float* __restrict__ segout, float inv_n) {
    int c = threadIdx.x;
    if (c < NCLS) {
        float s = 0.f;
        #pragma unroll 4
        for (int k = 0; k < HDIM; ++k) s = fmaf(colsum[k], Wp[c * HDIM + k], s);
        segout[c] = s * inv_n + bp[c];
    }
}

// CAM[c, n] = dot(Wp[c,:], h[n,:]) — 64 nodes/block, 10 classes/wave.
__global__ __launch_bounds__(256) void cam_kernel(
        const float* __restrict__ h, const float* __restrict__ Wp,
        float* __restrict__ out, int n) {
    __shared__ float hs[64][132];
    __shared__ float wp[NCLS * HDIM];
    const int tid = threadIdx.x;
    const int n0 = blockIdx.x * 64;
    for (int t = tid; t < NCLS * 32; t += 256)
        ((float4*)wp)[t] = ((const float4*)Wp)[t];
    for (int t = tid; t < 64 * 32; t += 256) {
        int r = t >> 5, c4 = t & 31;
        float4 v = {0.f, 0.f, 0.f, 0.f};
        if (n0 + r < n) v = ((const float4*)(h + (size_t)(n0 + r) * HDIM))[c4];
        *(float4*)&hs[r][c4 * 4] = v;
    }
    __syncthreads();
    const int nl = tid & 63;
    const int cb = (tid >> 6) * 10;
    float acc[10] = {};
    for (int k = 0; k < HDIM; k += 4) {
        float4 hv = *(const float4*)&hs[nl][k];
        #pragma unroll
        for (int c = 0; c < 10; ++c) {
            float4 wv = *(const float4*)&wp[(cb + c) * HDIM + k];
            acc[c] = fmaf(hv.x, wv.x, acc[c]);
            acc[c] = fmaf(hv.y, wv.y, acc[c]);
            acc[c] = fmaf(hv.z, wv.z, acc[c]);
            acc[c] = fmaf(hv.w, wv.w, acc[c]);
        }
    }
    int gn = n0 + nl;
    if (gn < n) {
        #pragma unroll
        for (int c = 0; c < 10; ++c)
            out[(size_t)(cb + c) * n + gn] = acc[c];
    }
}

// ---------------- launch ----------------

extern "C" void kernel_launch(void* const* d_in, const int* in_sizes, int n_in,
                              void* d_out, int out_size, void* d_ws, size_t ws_size,
                              hipStream_t stream) {
    const float* features = (const float*)d_in[0];
    const float* W1 = (const float*)d_in[1];
    const float* b1 = (const float*)d_in[2];
    const float* W2 = (const float*)d_in[3];
    const float* b2 = (const float*)d_in[4];
    const float* W3 = (const float*)d_in[5];
    const float* b3 = (const float*)d_in[6];
    const float* Wp = (const float*)d_in[7];
    const float* bp = (const float*)d_in[8];
    const int*   src = (const int*)d_in[9];
    const int*   dst = (const int*)d_in[10];

    const int N = in_sizes[0] / HDIM;
    const int E = in_sizes[9];
    float* out = (float*)d_out;

    // workspace carve-up
    char* ws = (char*)d_ws;
    size_t off = 0;
    int* out_deg  = (int*)(ws + off); off += (size_t)N * 4;
    int* in_deg   = (int*)(ws + off); off += (size_t)N * 4;
    float* colsum = (float*)(ws + off); off += 128 * 4;
    int* bsum     = (int*)(ws + off); off += 128 * 4;
    int* psum     = (int*)(ws + off); off += 128 * 4;
    int* row_ptr  = (int*)(ws + off); off += ((size_t)N + 1) * 4; off = (off + 15) & ~(size_t)15;
    int* col_idx  = (int*)(ws + off); off += (size_t)E * 4; off = (off + 15) & ~(size_t)15;
    float* out_norm = (float*)(ws + off); off += (size_t)N * 4;
    float* in_norm  = (float*)(ws + off); off += (size_t)N * 4; off = (off + 255) & ~(size_t)255;
    float* B1 = (float*)(ws + off); off += (size_t)N * HDIM * 4;
    float* B0 = (float*)(ws + off); off += (size_t)N * HDIM * 4;
    (void)ws_size; (void)n_in; (void)out_size;

    int* pos = (int*)B1;   // B1 unused until first gemm; reuse its space for pos[E]

    const int nzero = 2 * N + 128;
    zero_kernel<<<(nzero + 255) / 256, 256, 0, stream>>>((int*)ws, nzero);
    deg_kernel<<<((E + 3) / 4 + 255) / 256, 256, 0, stream>>>(src, dst, out_deg, in_deg, pos, E);
    norm_kernel<<<(N + 255) / 256, 256, 0, stream>>>(out_deg, in_deg, out_norm, in_norm, N);

    const int P = (N + 1023) / 1024;   // <= 128
    scan_part_kernel<<<P, 256, 0, stream>>>(in_deg, bsum, N);
    scan_mid_kernel<<<1, 128, 0, stream>>>(bsum, psum, row_ptr, P, N);
    scan_local_kernel<<<P, 256, 0, stream>>>(in_deg, psum, row_ptr, N);

    fill_kernel<<<((E + 3) / 4 + 255) / 256, 256, 0, stream>>>(src, dst, row_ptr, pos, col_idx, E);

    const int gemm_blocks = (N + 63) / 64;
    const int agg_blocks  = (N + 3) / 4;

    // layer 1
    gemm_kernel<<<gemm_blocks, 256, 0, stream>>>(features, W1, out_norm, B1, N);
    agg_kernel<<<agg_blocks, 256, 0, stream>>>(B1, row_ptr, col_idx, in_norm, b1, B0, N);
    // layer 2
    gemm_kernel<<<gemm_blocks, 256, 0, stream>>>(B0, W2, out_norm, B1, N);
    agg_kernel<<<agg_blocks, 256, 0, stream>>>(B1, row_ptr, col_idx, in_norm, b2, B0, N);
    // layer 3
    gemm_kernel<<<gemm_blocks, 256, 0, stream>>>(B0, W3, out_norm, B1, N);
    agg_kernel<<<agg_blocks, 256, 0, stream>>>(B1, row_ptr, col_idx, in_norm, b3, B0, N);

    // head
    colsum_kernel<<<512, 256, 0, stream>>>(B0, colsum, N);
    seg_kernel<<<1, 64, 0, stream>>>(colsum, Wp, bp, out, 1.0f / (float)N);
    cam_kernel<<<(N + 63) / 64, 256, 0, stream>>>(B0, Wp, out + NCLS, N);
}

// Round 3
// 804.734 us; speedup vs baseline: 1.2812x; 1.1468x over previous
//
#include <hip/hip_runtime.h>
#include <hip/hip_bf16.h>
#include <hip/hip_fp16.h>

// GCN: 3 layers of  h = relu(in_norm * A_pull( (out_norm*x) @ W ) + b)
// then seg_output = (mean_n h3) @ Wp^T + bp  and  CAM = Wp @ h3^T.
// CSR built per call (deg atomics yield per-edge slot -> fill atomic-free).
// Layers 1-2 use fp16 for the gather tensor (halves L2/L3 gather bytes);
// layer 3 is full fp32 to protect the CAM-facing precision.

#define HDIM 128
#define NCLS 40

// ---------------- graph preprocessing ----------------

__global__ void zero_kernel(int* __restrict__ p, int n) {
    int i = blockIdx.x * blockDim.x + threadIdx.x;
    if (i < n) p[i] = 0;
}

// 1 edge/thread: scattered atomics want max wave parallelism (R2 post-mortem).
__global__ void deg_kernel(const int* __restrict__ src, const int* __restrict__ dst,
                           int* __restrict__ out_deg, int* __restrict__ in_deg,
                           int* __restrict__ pos, int E) {
    int i = blockIdx.x * blockDim.x + threadIdx.x;
    if (i < E) {
        atomicAdd(&out_deg[src[i]], 1);
        pos[i] = atomicAdd(&in_deg[dst[i]], 1);
    }
}

__global__ void norm_kernel(const int* __restrict__ out_deg, const int* __restrict__ in_deg,
                            float* __restrict__ out_norm, float* __restrict__ in_norm, int n) {
    int i = blockIdx.x * blockDim.x + threadIdx.x;
    if (i < n) {
        out_norm[i] = 1.0f / sqrtf((float)max(out_deg[i], 1));
        in_norm[i]  = 1.0f / sqrtf((float)max(in_deg[i], 1));
    }
}

// ---- 3-pass exclusive scan over in_deg -> row_ptr ----

__global__ void scan_part_kernel(const int* __restrict__ cnt, int* __restrict__ bsum, int n) {
    const int tid = threadIdx.x;
    int base = blockIdx.x * 1024 + tid * 4;
    int s = 0;
    #pragma unroll
    for (int j = 0; j < 4; ++j) if (base + j < n) s += cnt[base + j];
    #pragma unroll
    for (int d = 1; d < 64; d <<= 1) s += __shfl_down(s, d, 64);
    __shared__ int ws[4];
    if ((tid & 63) == 0) ws[tid >> 6] = s;
    __syncthreads();
    if (tid == 0) bsum[blockIdx.x] = ws[0] + ws[1] + ws[2] + ws[3];
}

__global__ void scan_mid_kernel(const int* __restrict__ bsum, int* __restrict__ psum,
                                int* __restrict__ row_ptr, int P, int n) {
    const int tid = threadIdx.x;            // 0..127
    const int lane = tid & 63, w = tid >> 6;
    int v = (tid < P) ? bsum[tid] : 0;
    int incl = v;
    #pragma unroll
    for (int d = 1; d < 64; d <<= 1) {
        int o = __shfl_up(incl, d, 64);
        if (lane >= d) incl += o;
    }
    __shared__ int wtot[2];
    if (lane == 63) wtot[w] = incl;
    __syncthreads();
    int off = (w == 1) ? wtot[0] : 0;
    if (tid < P) psum[tid] = off + incl - v;
    if (tid == 0) row_ptr[n] = wtot[0] + wtot[1];
}

__global__ void scan_local_kernel(const int* __restrict__ cnt, const int* __restrict__ psum,
                                  int* __restrict__ row_ptr, int n) {
    const int tid = threadIdx.x;
    const int lane = tid & 63, w = tid >> 6;
    int base = blockIdx.x * 1024 + tid * 4;
    int v0 = (base     < n) ? cnt[base]     : 0;
    int v1 = (base + 1 < n) ? cnt[base + 1] : 0;
    int v2 = (base + 2 < n) ? cnt[base + 2] : 0;
    int v3 = (base + 3 < n) ? cnt[base + 3] : 0;
    int s = v0 + v1 + v2 + v3;
    int incl = s;
    #pragma unroll
    for (int d = 1; d < 64; d <<= 1) {
        int o = __shfl_up(incl, d, 64);
        if (lane >= d) incl += o;
    }
    __shared__ int ws[4];
    if (lane == 63) ws[w] = incl;
    __syncthreads();
    int off = psum[blockIdx.x];
    for (int j = 0; j < w; ++j) off += ws[j];
    int excl = off + incl - s;
    if (base     < n) row_ptr[base]     = excl;
    if (base + 1 < n) row_ptr[base + 1] = excl + v0;
    if (base + 2 < n) row_ptr[base + 2] = excl + v0 + v1;
    if (base + 3 < n) row_ptr[base + 3] = excl + v0 + v1 + v2;
}

// atomic-free CSR fill using precomputed pos, 1 edge/thread
__global__ void fill_kernel(const int* __restrict__ src, const int* __restrict__ dst,
                            const int* __restrict__ row_ptr, const int* __restrict__ pos,
                            int* __restrict__ col, int E) {
    int i = blockIdx.x * blockDim.x + threadIdx.x;
    if (i < E)
        col[row_ptr[dst[i]] + pos[i]] = src[i];
}

// ---------------- dense compute ----------------

// out[n,:] = (out_norm[n] * x[n,:]) @ W — 64 rows/block, W staged in 2 K-halves.
// OT = float or __half (layers 1-2 emit fp16 for the gather).
// In-place (out==x, fp32) is safe: a block only reads its own 64 rows, fully
// staged to LDS before the epilogue writes.
template <typename OT>
__global__ __launch_bounds__(256, 2) void gemm_kernel(
        const float* __restrict__ x, const float* __restrict__ W,
        const float* __restrict__ out_norm, OT* __restrict__ out, int n) {
    __shared__ float xs[64 * 132];    // +4 pad breaks bank aliasing
    __shared__ float wsm[64 * 128];
    const int tid = threadIdx.x;
    const int row0 = blockIdx.x * 64;

    for (int t = tid; t < 64 * 32; t += 256) {
        int r = t >> 5, c4 = t & 31;
        int gr = row0 + r;
        float4 v = {0.f, 0.f, 0.f, 0.f};
        if (gr < n) {
            v = ((const float4*)(x + (size_t)gr * HDIM))[c4];
            float s = out_norm[gr];
            v.x *= s; v.y *= s; v.z *= s; v.w *= s;
        }
        *(float4*)&xs[r * 132 + c4 * 4] = v;
    }

    const int cg = tid & 15, rg = tid >> 4;
    const int c0 = cg * 8, r0 = rg * 4;
    float acc[4][8] = {};

    for (int kh = 0; kh < 2; ++kh) {
        __syncthreads();
        for (int t = tid; t < 64 * 32; t += 256)
            ((float4*)wsm)[t] = ((const float4*)(W + kh * 64 * HDIM))[t];
        __syncthreads();
        #pragma unroll 2
        for (int kk4 = 0; kk4 < 16; ++kk4) {
            float xr[4][4];
            #pragma unroll
            for (int i = 0; i < 4; ++i)
                *(float4*)&xr[i][0] = *(const float4*)&xs[(r0 + i) * 132 + kh * 64 + kk4 * 4];
            #pragma unroll
            for (int q = 0; q < 4; ++q) {
                float wv[8];
                *(float4*)&wv[0] = *(const float4*)&wsm[(kk4 * 4 + q) * 128 + c0];
                *(float4*)&wv[4] = *(const float4*)&wsm[(kk4 * 4 + q) * 128 + c0 + 4];
                #pragma unroll
                for (int i = 0; i < 4; ++i)
                    #pragma unroll
                    for (int j = 0; j < 8; ++j)
                        acc[i][j] = fmaf(xr[i][q], wv[j], acc[i][j]);
            }
        }
    }

    #pragma unroll
    for (int i = 0; i < 4; ++i) {
        int gr = row0 + r0 + i;
        if (gr < n) {
            if constexpr (sizeof(OT) == 2) {
                __half2 p[4];
                #pragma unroll
                for (int q = 0; q < 4; ++q) {
                    __half2 t2;
                    t2.x = __float2half(acc[i][2 * q]);
                    t2.y = __float2half(acc[i][2 * q + 1]);
                    p[q] = t2;
                }
                *(float4*)((__half*)out + (size_t)gr * HDIM + c0) = *(float4*)p;
            } else {
                float4 v0 = {acc[i][0], acc[i][1], acc[i][2], acc[i][3]};
                float4 v1 = {acc[i][4], acc[i][5], acc[i][6], acc[i][7]};
                float4* op = (float4*)((float*)out + (size_t)gr * HDIM + c0);
                op[0] = v0; op[1] = v1;
            }
        }
    }
}

// fp16 gather: h[n,:] = relu(in_norm[n]*sum t[col[e],:] + b) — one wave/node,
// 4 edges per wave-load (16 lanes x 16 B = one 256-B fp16 row), fp32 accum.
__global__ __launch_bounds__(256) void agg_h_kernel(
        const __half* __restrict__ t, const int* __restrict__ row_ptr,
        const int* __restrict__ col, const float* __restrict__ in_norm,
        const float* __restrict__ bias, float* __restrict__ h, int n) {
    int node = blockIdx.x * 4 + (threadIdx.x >> 6);
    if (node >= n) return;
    const int lane = threadIdx.x & 63;
    const int eg = lane >> 4;       // edge group 0..3
    const int fq = lane & 15;       // feature quarter: halfs [fq*8, fq*8+8)
    const int beg = row_ptr[node], end = row_ptr[node + 1];
    float acc0[8] = {}, acc1[8] = {};
    for (int e = beg; e < end; e += 64) {
        int cnt = min(64, end - e);
        int ci = (lane < cnt) ? col[e + lane] : 0;
        for (int j = 0; j < cnt; j += 8) {
            int s0 = __shfl(ci, j + eg, 64);
            int s1 = __shfl(ci, j + 4 + eg, 64);
            float4 r0 = {0.f, 0.f, 0.f, 0.f}, r1 = {0.f, 0.f, 0.f, 0.f};
            if (j + eg < cnt)     r0 = ((const float4*)(t + (size_t)s0 * HDIM))[fq];
            if (j + 4 + eg < cnt) r1 = ((const float4*)(t + (size_t)s1 * HDIM))[fq];
            const __half2* p0 = (const __half2*)&r0;
            const __half2* p1 = (const __half2*)&r1;
            #pragma unroll
            for (int q = 0; q < 4; ++q) {
                float2 f0 = __half22float2(p0[q]);
                float2 f1 = __half22float2(p1[q]);
                acc0[2 * q]     += f0.x; acc0[2 * q + 1] += f0.y;
                acc1[2 * q]     += f1.x; acc1[2 * q + 1] += f1.y;
            }
        }
    }
    #pragma unroll
    for (int q = 0; q < 8; ++q) acc0[q] += acc1[q];
    #pragma unroll
    for (int q = 0; q < 8; ++q) acc0[q] += __shfl_xor(acc0[q], 16, 64);
    #pragma unroll
    for (int q = 0; q < 8; ++q) acc0[q] += __shfl_xor(acc0[q], 32, 64);
    if (eg == 0) {   // lanes 0..15 hold totals for features [fq*8, fq*8+8)
        float inn = in_norm[node];
        float4 b0 = ((const float4*)bias)[2 * fq];
        float4 b1 = ((const float4*)bias)[2 * fq + 1];
        float4 o0, o1;
        o0.x = fmaxf(acc0[0] * inn + b0.x, 0.f);
        o0.y = fmaxf(acc0[1] * inn + b0.y, 0.f);
        o0.z = fmaxf(acc0[2] * inn + b0.z, 0.f);
        o0.w = fmaxf(acc0[3] * inn + b0.w, 0.f);
        o1.x = fmaxf(acc0[4] * inn + b1.x, 0.f);
        o1.y = fmaxf(acc0[5] * inn + b1.y, 0.f);
        o1.z = fmaxf(acc0[6] * inn + b1.z, 0.f);
        o1.w = fmaxf(acc0[7] * inn + b1.w, 0.f);
        float4* op = (float4*)(h + (size_t)node * HDIM);
        op[2 * fq] = o0;
        op[2 * fq + 1] = o1;
    }
}

// fp32 gather (layer 3): one wave/node, half-wave per edge, float4 lanes.
__global__ __launch_bounds__(256) void agg_kernel(
        const float* __restrict__ t, const int* __restrict__ row_ptr,
        const int* __restrict__ col, const float* __restrict__ in_norm,
        const float* __restrict__ bias, float* __restrict__ h, int n) {
    int node = blockIdx.x * 4 + (threadIdx.x >> 6);
    if (node >= n) return;
    const int lane = threadIdx.x & 63;
    const int half = lane >> 5;
    const int fl = lane & 31;
    const int beg = row_ptr[node], end = row_ptr[node + 1];
    float4 acc0 = {0.f, 0.f, 0.f, 0.f}, acc1 = {0.f, 0.f, 0.f, 0.f};
    for (int e = beg; e < end; e += 64) {
        int cnt = min(64, end - e);
        int ci = (lane < cnt) ? col[e + lane] : 0;
        int j = 0;
        for (; j + 3 < cnt; j += 4) {
            int s0 = __shfl(ci, j + half, 64);
            int s1 = __shfl(ci, j + 2 + half, 64);
            float4 v0 = ((const float4*)(t + (size_t)s0 * HDIM))[fl];
            float4 v1 = ((const float4*)(t + (size_t)s1 * HDIM))[fl];
            acc0.x += v0.x; acc0.y += v0.y; acc0.z += v0.z; acc0.w += v0.w;
            acc1.x += v1.x; acc1.y += v1.y; acc1.z += v1.z; acc1.w += v1.w;
        }
        for (; j + 1 < cnt; j += 2) {
            int s0 = __shfl(ci, j + half, 64);
            float4 v0 = ((const float4*)(t + (size_t)s0 * HDIM))[fl];
            acc0.x += v0.x; acc0.y += v0.y; acc0.z += v0.z; acc0.w += v0.w;
        }
        if (j < cnt) {
            int s0 = __shfl(ci, j, 64);
            if (half == 0) {
                float4 v0 = ((const float4*)(t + (size_t)s0 * HDIM))[fl];
                acc0.x += v0.x; acc0.y += v0.y; acc0.z += v0.z; acc0.w += v0.w;
            }
        }
    }
    acc0.x += acc1.x; acc0.y += acc1.y; acc0.z += acc1.z; acc0.w += acc1.w;
    float ox = __shfl(acc0.x, fl + 32, 64);
    float oy = __shfl(acc0.y, fl + 32, 64);
    float oz = __shfl(acc0.z, fl + 32, 64);
    float ow = __shfl(acc0.w, fl + 32, 64);
    if (half == 0) {
        float inn = in_norm[node];
        float4 bb = ((const float4*)bias)[fl];
        float4 res;
        res.x = fmaxf((acc0.x + ox) * inn + bb.x, 0.f);
        res.y = fmaxf((acc0.y + oy) * inn + bb.y, 0.f);
        res.z = fmaxf((acc0.z + oz) * inn + bb.z, 0.f);
        res.w = fmaxf((acc0.w + ow) * inn + bb.w, 0.f);
        ((float4*)(h + (size_t)node * HDIM))[fl] = res;
    }
}

// column sums of h (for mean over nodes)
__global__ void colsum_kernel(const float* __restrict__ h, float* __restrict__ colsum, int n) {
    int c = threadIdx.x & 127;
    int rstart = blockIdx.x * 2 + (threadIdx.x >> 7);
    float s = 0.f;
    for (int r = rstart; r < n; r += gridDim.x * 2)
        s += h[(size_t)r * HDIM + c];
    atomicAdd(&colsum[c], s);
}

__global__ void seg_kernel(const float* __restrict__ colsum, const float* __restrict__ Wp,
                           const float* __restrict__ bp, float* __restrict__ segout, float inv_n) {
    int c = threadIdx.x;
    if (c < NCLS) {
        float s = 0.f;
        #pragma unroll 4
        for (int k = 0; k < HDIM; ++k) s = fmaf(colsum[k], Wp[c * HDIM + k], s);
        segout[c] = s * inv_n + bp[c];
    }
}

// CAM[c, n] = dot(Wp[c,:], h[n,:]) — 64 nodes/block, 10 classes/wave.
__global__ __launch_bounds__(256) void cam_kernel(
        const float* __restrict__ h, const float* __restrict__ Wp,
        float* __restrict__ out, int n) {
    __shared__ float hs[64][132];
    __shared__ float wp[NCLS * HDIM];
    const int tid = threadIdx.x;
    const int n0 = blockIdx.x * 64;
    for (int t = tid; t < NCLS * 32; t += 256)
        ((float4*)wp)[t] = ((const float4*)Wp)[t];
    for (int t = tid; t < 64 * 32; t += 256) {
        int r = t >> 5, c4 = t & 31;
        float4 v = {0.f, 0.f, 0.f, 0.f};
        if (n0 + r < n) v = ((const float4*)(h + (size_t)(n0 + r) * HDIM))[c4];
        *(float4*)&hs[r][c4 * 4] = v;
    }
    __syncthreads();
    const int nl = tid & 63;
    const int cb = (tid >> 6) * 10;
    float acc[10] = {};
    for (int k = 0; k < HDIM; k += 4) {
        float4 hv = *(const float4*)&hs[nl][k];
        #pragma unroll
        for (int c = 0; c < 10; ++c) {
            float4 wv = *(const float4*)&wp[(cb + c) * HDIM + k];
            acc[c] = fmaf(hv.x, wv.x, acc[c]);
            acc[c] = fmaf(hv.y, wv.y, acc[c]);
            acc[c] = fmaf(hv.z, wv.z, acc[c]);
            acc[c] = fmaf(hv.w, wv.w, acc[c]);
        }
    }
    int gn = n0 + nl;
    if (gn < n) {
        #pragma unroll
        for (int c = 0; c < 10; ++c)
            out[(size_t)(cb + c) * n + gn] = acc[c];
    }
}

// ---------------- launch ----------------

extern "C" void kernel_launch(void* const* d_in, const int* in_sizes, int n_in,
                              void* d_out, int out_size, void* d_ws, size_t ws_size,
                              hipStream_t stream) {
    const float* features = (const float*)d_in[0];
    const float* W1 = (const float*)d_in[1];
    const float* b1 = (const float*)d_in[2];
    const float* W2 = (const float*)d_in[3];
    const float* b2 = (const float*)d_in[4];
    const float* W3 = (const float*)d_in[5];
    const float* b3 = (const float*)d_in[6];
    const float* Wp = (const float*)d_in[7];
    const float* bp = (const float*)d_in[8];
    const int*   src = (const int*)d_in[9];
    const int*   dst = (const int*)d_in[10];

    const int N = in_sizes[0] / HDIM;
    const int E = in_sizes[9];
    float* out = (float*)d_out;

    // workspace carve-up
    char* ws = (char*)d_ws;
    size_t off = 0;
    int* out_deg  = (int*)(ws + off); off += (size_t)N * 4;
    int* in_deg   = (int*)(ws + off); off += (size_t)N * 4;
    float* colsum = (float*)(ws + off); off += 128 * 4;
    int* bsum     = (int*)(ws + off); off += 128 * 4;
    int* psum     = (int*)(ws + off); off += 128 * 4;
    int* row_ptr  = (int*)(ws + off); off += ((size_t)N + 1) * 4; off = (off + 15) & ~(size_t)15;
    int* col_idx  = (int*)(ws + off); off += (size_t)E * 4; off = (off + 15) & ~(size_t)15;
    float* out_norm = (float*)(ws + off); off += (size_t)N * 4;
    float* in_norm  = (float*)(ws + off); off += (size_t)N * 4; off = (off + 255) & ~(size_t)255;
    __half* Bh = (__half*)(ws + off); off += (size_t)N * HDIM * 2; off = (off + 255) & ~(size_t)255;
    float* F0 = (float*)(ws + off); off += (size_t)N * HDIM * 4;
    float* F1 = (float*)(ws + off); off += (size_t)N * HDIM * 4;
    (void)ws_size; (void)n_in; (void)out_size;

    int* pos = (int*)F1;   // F1 unused until layer-3 agg; reuse for pos[E]

    const int nzero = 2 * N + 128;
    zero_kernel<<<(nzero + 255) / 256, 256, 0, stream>>>((int*)ws, nzero);
    deg_kernel<<<(E + 255) / 256, 256, 0, stream>>>(src, dst, out_deg, in_deg, pos, E);
    norm_kernel<<<(N + 255) / 256, 256, 0, stream>>>(out_deg, in_deg, out_norm, in_norm, N);

    const int P = (N + 1023) / 1024;   // <= 128
    scan_part_kernel<<<P, 256, 0, stream>>>(in_deg, bsum, N);
    scan_mid_kernel<<<1, 128, 0, stream>>>(bsum, psum, row_ptr, P, N);
    scan_local_kernel<<<P, 256, 0, stream>>>(in_deg, psum, row_ptr, N);

    fill_kernel<<<(E + 255) / 256, 256, 0, stream>>>(src, dst, row_ptr, pos, col_idx, E);

    const int gemm_blocks = (N + 63) / 64;
    const int agg_blocks  = (N + 3) / 4;

    // layer 1 (fp16 gather tensor)
    gemm_kernel<__half><<<gemm_blocks, 256, 0, stream>>>(features, W1, out_norm, Bh, N);
    agg_h_kernel<<<agg_blocks, 256, 0, stream>>>(Bh, row_ptr, col_idx, in_norm, b1, F0, N);
    // layer 2 (fp16 gather tensor)
    gemm_kernel<__half><<<gemm_blocks, 256, 0, stream>>>(F0, W2, out_norm, Bh, N);
    agg_h_kernel<<<agg_blocks, 256, 0, stream>>>(Bh, row_ptr, col_idx, in_norm, b2, F0, N);
    // layer 3 (fp32, gemm in-place on F0)
    gemm_kernel<float><<<gemm_blocks, 256, 0, stream>>>(F0, W3, out_norm, F0, N);
    agg_kernel<<<agg_blocks, 256, 0, stream>>>(F0, row_ptr, col_idx, in_norm, b3, F1, N);

    // head (reads h3 = F1)
    colsum_kernel<<<512, 256, 0, stream>>>(F1, colsum, N);
    seg_kernel<<<1, 64, 0, stream>>>(colsum, Wp, bp, out, 1.0f / (float)N);
    cam_kernel<<<(N + 63) / 64, 256, 0, stream>>>(F1, Wp, out + NCLS, N);
}